// Round 4
// baseline (767.040 us; speedup 1.0000x reference)
//
#include <hip/hip_runtime.h>

#define N_NODES 100000
#define N_EDGES 1600000
#define IN_DIM 160
#define HID 128
#define BN_EPS 1e-5f

#define M_PAD 100096   // 782 * 128 rows (GEMM block = 128 rows)
#define NBUCK 196      // 512-node buckets (196*512 = 100352 >= N_NODES)
#define BSH 9
#define EPB 8192       // edges per block in hist/scatter kernels
#define NHB (NBUCK * NBUCK)
#define K2CHUNK 38     // 1024*38 = 38912 >= NHB
#define NPN 4          // nodes per wave in agg kernel
#define LPAD 260       // LDS repack row stride (ushorts): 520B -> quad rows 8 banks apart

typedef unsigned int uint;
typedef unsigned short ushort;
typedef __attribute__((ext_vector_type(8))) short bf16x8;
typedef __attribute__((ext_vector_type(4))) float f32x4;

__device__ __forceinline__ ushort bf16rn(float f) {
    uint u = __float_as_uint(f);
    u += 0x7fffu + ((u >> 16) & 1u);
    return (ushort)(u >> 16);
}

// ---------------------------------------------------------------------------
// CSR build via two-level bucket sort.
// ---------------------------------------------------------------------------

__global__ __launch_bounds__(256) void hist_kernel(const int* __restrict__ dst,
                                                   int* __restrict__ ghist) {
    __shared__ int hist[NBUCK];
    int b = blockIdx.x, t = threadIdx.x;
    for (int i = t; i < NBUCK; i += 256) hist[i] = 0;
    __syncthreads();
    int e0 = b * EPB;
    for (int i = 0; i < EPB; i += 256) {
        int e = e0 + i + t;
        if (e < N_EDGES) atomicAdd(&hist[dst[e] >> BSH], 1);
    }
    __syncthreads();
    for (int i = t; i < NBUCK; i += 256) ghist[i * NBUCK + b] = hist[i];
}

// Single block (1024 thr): exclusive scan of NHB ints in-place + bucket bases.
__global__ __launch_bounds__(1024) void scan_hist_kernel(int* __restrict__ ghist,
                                                         int* __restrict__ gbb) {
    __shared__ int tsum[1024];
    int t = threadIdx.x;
    int base = t * K2CHUNK;
    int s = 0;
    for (int i = 0; i < K2CHUNK; ++i) {
        int idx = base + i;
        if (idx < NHB) s += ghist[idx];
    }
    tsum[t] = s;
    __syncthreads();
    for (int off = 1; off < 1024; off <<= 1) {
        int v = (t >= off) ? tsum[t - off] : 0;
        __syncthreads();
        tsum[t] += v;
        __syncthreads();
    }
    int excl = (t > 0) ? tsum[t - 1] : 0;
    for (int i = 0; i < K2CHUNK; ++i) {
        int idx = base + i;
        if (idx < NHB) {
            int v = ghist[idx];
            ghist[idx] = excl;
            if ((idx % NBUCK) == 0) gbb[idx / NBUCK] = excl;
            excl += v;
        }
    }
    if (t == 0) gbb[NBUCK] = N_EDGES;
}

__global__ __launch_bounds__(256) void scatter_kernel(const int* __restrict__ src,
                                                      const int* __restrict__ dst,
                                                      const int* __restrict__ ghist,
                                                      uint* __restrict__ scat) {
    __shared__ int base[NBUCK];
    __shared__ int fill[NBUCK];
    int b = blockIdx.x, t = threadIdx.x;
    for (int i = t; i < NBUCK; i += 256) { base[i] = ghist[i * NBUCK + b]; fill[i] = 0; }
    __syncthreads();
    int e0 = b * EPB;
    for (int i = 0; i < EPB; i += 256) {
        int e = e0 + i + t;
        if (e < N_EDGES) {
            int d = dst[e];
            int sv = src[e];
            int bk = d >> BSH;
            int lp = atomicAdd(&fill[bk], 1);
            scat[base[bk] + lp] = (uint)sv | ((uint)(d & 511) << 17);
        }
    }
}

__global__ __launch_bounds__(256) void bucket_csr_kernel(const uint* __restrict__ scat,
                                                         const int* __restrict__ gbb,
                                                         int* __restrict__ rowptr,
                                                         int* __restrict__ eidx) {
    __shared__ int cnt[512], fl[512], pref[512];
    __shared__ int ts[256];
    int b = blockIdx.x, t = threadIdx.x;
    int beg = gbb[b], end = gbb[b + 1];
    cnt[t] = 0; cnt[t + 256] = 0;
    __syncthreads();
    for (int i = beg + t; i < end; i += 256)
        atomicAdd(&cnt[scat[i] >> 17], 1);
    __syncthreads();
    int c0 = cnt[2 * t], c1 = cnt[2 * t + 1];
    ts[t] = c0 + c1;
    __syncthreads();
    for (int off = 1; off < 256; off <<= 1) {
        int v = (t >= off) ? ts[t - off] : 0;
        __syncthreads();
        ts[t] += v;
        __syncthreads();
    }
    int ex = (t > 0) ? ts[t - 1] : 0;
    pref[2 * t] = ex;
    pref[2 * t + 1] = ex + c0;
    fl[t] = 0; fl[t + 256] = 0;
    int g0 = b * 512 + 2 * t;
    if (g0 <= N_NODES) rowptr[g0] = beg + ex;
    if (g0 + 1 <= N_NODES) rowptr[g0 + 1] = beg + ex + c0;
    __syncthreads();
    for (int i = beg + t; i < end; i += 256) {
        uint w = scat[i];
        int nl = (int)(w >> 17);
        int lp = atomicAdd(&fl[nl], 1);
        eidx[beg + pref[nl] + lp] = (int)(w & 0x1FFFFu);
    }
}

// ---------------------------------------------------------------------------
// Prep
// ---------------------------------------------------------------------------
__global__ void prep_weights_kernel(const float* __restrict__ wl, const float* __restrict__ wr,
                                    ushort* __restrict__ Bt, int K) {
    int n = blockIdx.y;
    int k = blockIdx.x * 64 + threadIdx.x;
    if (k < K) {
        float v = (n < HID) ? wl[k * HID + n] : wr[k * HID + (n - HID)];
        Bt[n * K + k] = bf16rn(v);
    }
}

__global__ void bn_prep_kernel(const float* __restrict__ bl, const float* __restrict__ g,
                               const float* __restrict__ be, const float* __restrict__ rm,
                               const float* __restrict__ rv, float* __restrict__ scale,
                               float* __restrict__ shift) {
    int j = threadIdx.x;
    float s = g[j] * rsqrtf(rv[j] + BN_EPS);
    scale[j] = s;
    shift[j] = (bl[j] - rm[j]) * s + be[j];
}

// ---------------------------------------------------------------------------
// GEMM: [tl | troot] = A @ [wl | wr].  tl, troot: separate dense [M][128] bf16
// buffers (gather side dense for L2 set utilization). LDS repack epilogue ->
// fully-coalesced 256B row stores.
// ---------------------------------------------------------------------------
template <int K, bool AFP32>
__global__ __launch_bounds__(256) void gemm_kernel(const void* __restrict__ A_,
                                                   const ushort* __restrict__ Bt,
                                                   ushort* __restrict__ tl,
                                                   ushort* __restrict__ troot) {
    __shared__ ushort lds[4][16][LPAD];  // ~33 KB
    const int lane = threadIdx.x & 63;
    const int wv = threadIdx.x >> 6;
    const int col = lane & 15;
    const int kq = (lane >> 4) * 8;
    const int m0 = blockIdx.x * 128 + wv * 32 + col;
    f32x4 acc[2][16];
#pragma unroll
    for (int a = 0; a < 2; ++a)
#pragma unroll
        for (int t = 0; t < 16; ++t) acc[a][t] = (f32x4){0.f, 0.f, 0.f, 0.f};

#pragma unroll
    for (int k0 = 0; k0 < K; k0 += 32) {
        int kk = k0 + kq;
        bf16x8 a0, a1;
        if (AFP32) {
            const float* A = (const float*)A_;
            float4 z = make_float4(0.f, 0.f, 0.f, 0.f);
            float4 f00 = z, f01 = z, f10 = z, f11 = z;
            if (m0 < N_NODES) {
                f00 = *(const float4*)(A + (size_t)m0 * K + kk);
                f01 = *(const float4*)(A + (size_t)m0 * K + kk + 4);
            }
            if (m0 + 16 < N_NODES) {
                f10 = *(const float4*)(A + (size_t)(m0 + 16) * K + kk);
                f11 = *(const float4*)(A + (size_t)(m0 + 16) * K + kk + 4);
            }
            a0[0] = (short)bf16rn(f00.x); a0[1] = (short)bf16rn(f00.y);
            a0[2] = (short)bf16rn(f00.z); a0[3] = (short)bf16rn(f00.w);
            a0[4] = (short)bf16rn(f01.x); a0[5] = (short)bf16rn(f01.y);
            a0[6] = (short)bf16rn(f01.z); a0[7] = (short)bf16rn(f01.w);
            a1[0] = (short)bf16rn(f10.x); a1[1] = (short)bf16rn(f10.y);
            a1[2] = (short)bf16rn(f10.z); a1[3] = (short)bf16rn(f10.w);
            a1[4] = (short)bf16rn(f11.x); a1[5] = (short)bf16rn(f11.y);
            a1[6] = (short)bf16rn(f11.z); a1[7] = (short)bf16rn(f11.w);
        } else {
            const ushort* A = (const ushort*)A_;
            a0 = *(const bf16x8*)(A + (size_t)m0 * K + kk);
            a1 = *(const bf16x8*)(A + (size_t)(m0 + 16) * K + kk);
        }
#pragma unroll
        for (int t = 0; t < 16; ++t) {
            bf16x8 bfr = *(const bf16x8*)(Bt + (size_t)(t * 16 + col) * K + kk);
            acc[0][t] = __builtin_amdgcn_mfma_f32_16x16x32_bf16(a0, bfr, acc[0][t], 0, 0, 0);
            acc[1][t] = __builtin_amdgcn_mfma_f32_16x16x32_bf16(a1, bfr, acc[1][t], 0, 0, 0);
        }
    }

    // Epilogue: repack per-wave 16x256 C chunk through LDS (row stride LPAD
    // -> quad rows land 8 banks apart: all 32 banks, 2 lanes/word = free).
    const int quad = lane >> 4;
#pragma unroll
    for (int mt = 0; mt < 2; ++mt) {
#pragma unroll
        for (int tt = 0; tt < 16; ++tt)
#pragma unroll
            for (int r = 0; r < 4; ++r)
                lds[wv][quad * 4 + r][tt * 16 + col] = bf16rn(acc[mt][tt][r]);
        int mbase = blockIdx.x * 128 + wv * 32 + mt * 16;
        __builtin_amdgcn_s_barrier();  // wave-local ordering only; cheap
#pragma unroll
        for (int i = 0; i < 8; ++i) {
            int lin = i * 64 + lane;
            int row = lin >> 5;   // 2 rows per inst
            int cb = lin & 31;    // 8-ushort group within 256-col row
            bf16x8 v = *(const bf16x8*)&lds[wv][row][cb * 8];
            int m = mbase + row;
            ushort* dstp = (cb < 16) ? (tl + (size_t)m * HID + cb * 8)
                                     : (troot + (size_t)m * HID + (cb - 16) * 8);
            *(bf16x8*)dstp = v;
        }
    }
}

// ---------------------------------------------------------------------------
// Aggregation + BN + ReLU (+ fused final linear). Gather from dense tl.
// ---------------------------------------------------------------------------
template <bool FINAL>
__global__ __launch_bounds__(256) void agg_kernel(
    const ushort* __restrict__ tl_, const ushort* __restrict__ troot_,
    const int* __restrict__ rowptr, const int* __restrict__ eidx,
    const float* __restrict__ bnscale, const float* __restrict__ bnshift,
    const float* __restrict__ linw, const float* __restrict__ linb,
    ushort* __restrict__ hout, float* __restrict__ out) {
    const uint* tl = (const uint*)tl_;      // row = 64 uints (128 bf16)
    const uint* tr = (const uint*)troot_;
    const int lane = threadIdx.x & 63;
    const int wv = (blockIdx.x * 256 + (int)threadIdx.x) >> 6;
    float2 sc = *(const float2*)(bnscale + 2 * lane);
    float2 sh = *(const float2*)(bnshift + 2 * lane);
    float w0 = 0.f, w1 = 0.f, lb = 0.f;
    if (FINAL) {
        float2 wvv = *(const float2*)(linw + 2 * lane);
        w0 = wvv.x; w1 = wvv.y; lb = linb[0];
    }
    const int n0 = wv * NPN;
    for (int i = 0; i < NPN; ++i) {
        int n = n0 + i;
        if (n >= N_NODES) return;
        int beg = __builtin_amdgcn_readfirstlane(rowptr[n]);
        int end = __builtin_amdgcn_readfirstlane(rowptr[n + 1]);
        float s0 = 0.f, s1 = 0.f;
        for (int e = beg; e < end; e += 8) {
            int c = end - e;
            uint u[8];
#pragma unroll
            for (int j = 0; j < 8; ++j) {
                int ee = (j < c) ? (e + j) : beg;
                int s = eidx[ee];
                u[j] = tl[(size_t)s * 64 + lane];
            }
#pragma unroll
            for (int j = 0; j < 8; ++j) {
                float f0 = __uint_as_float(u[j] << 16);
                float f1 = __uint_as_float(u[j] & 0xffff0000u);
                if (j < c) { s0 += f0; s1 += f1; }
            }
        }
        int deg = end - beg;
        float inv = 1.0f / (float)max(deg, 1);
        uint ur = tr[(size_t)n * 64 + lane];
        float r0 = __uint_as_float(ur << 16);
        float r1 = __uint_as_float(ur & 0xffff0000u);
        float o0 = fmaxf((s0 * inv + r0) * sc.x + sh.x, 0.f);
        float o1 = fmaxf((s1 * inv + r1) * sc.y + sh.y, 0.f);
        if (FINAL) {
            float p = o0 * w0 + o1 * w1;
#pragma unroll
            for (int off = 32; off; off >>= 1) p += __shfl_down(p, off);
            if (lane == 0) out[n] = p + lb;
        } else {
            uint pack = (uint)bf16rn(o0) | ((uint)bf16rn(o1) << 16);
            ((uint*)hout)[(size_t)n * 64 + lane] = pack;
        }
    }
}

// ---------------------------------------------------------------------------

extern "C" void kernel_launch(void* const* d_in, const int* in_sizes, int n_in,
                              void* d_out, int out_size, void* d_ws, size_t ws_size,
                              hipStream_t stream) {
    const float* x    = (const float*)d_in[0];
    const int*   ei   = (const int*)d_in[1];
    const int*   esrc = ei;
    const int*   edst = ei + N_EDGES;
    const float* wl[3]; const float* wr[3]; const float* bl[3];
    const float* g[3];  const float* be[3]; const float* rm[3]; const float* rv[3];
    for (int i = 0; i < 3; ++i) {
        wl[i] = (const float*)d_in[2 + 7 * i];
        wr[i] = (const float*)d_in[3 + 7 * i];
        bl[i] = (const float*)d_in[4 + 7 * i];
        g[i]  = (const float*)d_in[5 + 7 * i];
        be[i] = (const float*)d_in[6 + 7 * i];
        rm[i] = (const float*)d_in[7 + 7 * i];
        rv[i] = (const float*)d_in[8 + 7 * i];
    }
    const float* lin_w = (const float*)d_in[23];
    const float* lin_b = (const float*)d_in[24];
    float* out = (float*)d_out;

    // Workspace carve-up (~91 MB total).
    char* ws = (char*)d_ws;
    size_t off = 0;
    auto carve = [&](size_t bytes) -> void* {
        void* p = ws + off;
        off += (bytes + 255) & ~(size_t)255;
        return p;
    };
    int*    rowptr = (int*)carve((size_t)(N_NODES + 8) * sizeof(int));
    int*    eidx   = (int*)carve((size_t)N_EDGES * sizeof(int));
    uint*   scat   = (uint*)carve((size_t)N_EDGES * sizeof(uint));
    int*    ghist  = (int*)carve((size_t)(1024 * K2CHUNK) * sizeof(int));
    int*    gbb    = (int*)carve((NBUCK + 4) * sizeof(int));
    ushort* tl     = (ushort*)carve((size_t)M_PAD * HID * sizeof(ushort));
    ushort* troot  = (ushort*)carve((size_t)M_PAD * HID * sizeof(ushort));
    ushort* h      = (ushort*)carve((size_t)M_PAD * HID * sizeof(ushort));
    ushort* Bt0    = (ushort*)carve(256 * IN_DIM * sizeof(ushort));
    ushort* Bt1    = (ushort*)carve(256 * HID * sizeof(ushort));
    ushort* Bt2    = (ushort*)carve(256 * HID * sizeof(ushort));
    float*  bnsc   = (float*)carve(3 * HID * sizeof(float));
    float*  bnsh   = (float*)carve(3 * HID * sizeof(float));
    (void)ws_size; (void)n_in; (void)in_sizes; (void)out_size;

    hist_kernel<<<NBUCK, 256, 0, stream>>>(edst, ghist);
    scan_hist_kernel<<<1, 1024, 0, stream>>>(ghist, gbb);
    scatter_kernel<<<NBUCK, 256, 0, stream>>>(esrc, edst, ghist, scat);
    bucket_csr_kernel<<<NBUCK, 256, 0, stream>>>(scat, gbb, rowptr, eidx);

    prep_weights_kernel<<<dim3((IN_DIM + 63) / 64, 256), 64, 0, stream>>>(wl[0], wr[0], Bt0, IN_DIM);
    prep_weights_kernel<<<dim3((HID + 63) / 64, 256), 64, 0, stream>>>(wl[1], wr[1], Bt1, HID);
    prep_weights_kernel<<<dim3((HID + 63) / 64, 256), 64, 0, stream>>>(wl[2], wr[2], Bt2, HID);
    bn_prep_kernel<<<1, HID, 0, stream>>>(bl[0], g[0], be[0], rm[0], rv[0], bnsc, bnsh);
    bn_prep_kernel<<<1, HID, 0, stream>>>(bl[1], g[1], be[1], rm[1], rv[1], bnsc + HID, bnsh + HID);
    bn_prep_kernel<<<1, HID, 0, stream>>>(bl[2], g[2], be[2], rm[2], rv[2], bnsc + 2 * HID, bnsh + 2 * HID);

    const int GEMM_GRID = M_PAD / 128;          // 782
    const int AGG_GRID = N_NODES / (4 * NPN);   // 6250

    gemm_kernel<IN_DIM, true><<<GEMM_GRID, 256, 0, stream>>>(x, Bt0, tl, troot);
    agg_kernel<false><<<AGG_GRID, 256, 0, stream>>>(tl, troot, rowptr, eidx, bnsc, bnsh,
                                                    nullptr, nullptr, h, nullptr);
    gemm_kernel<HID, false><<<GEMM_GRID, 256, 0, stream>>>(h, Bt1, tl, troot);
    agg_kernel<false><<<AGG_GRID, 256, 0, stream>>>(tl, troot, rowptr, eidx, bnsc + HID, bnsh + HID,
                                                    nullptr, nullptr, h, nullptr);
    gemm_kernel<HID, false><<<GEMM_GRID, 256, 0, stream>>>(h, Bt2, tl, troot);
    agg_kernel<true><<<AGG_GRID, 256, 0, stream>>>(tl, troot, rowptr, eidx, bnsc + 2 * HID, bnsh + 2 * HID,
                                                   lin_w, lin_b, nullptr, out);
}

// Round 5
// 576.260 us; speedup vs baseline: 1.3311x; 1.3311x over previous
//
#include <hip/hip_runtime.h>

#define N_NODES 100000
#define N_EDGES 1600000
#define IN_DIM 160
#define HID 128
#define BN_EPS 1e-5f

#define M_PAD 100096   // 782 * 128 rows (GEMM block = 128 rows)
#define NBUCK 196      // 512-node buckets (196*512 = 100352 >= N_NODES)
#define BSH 9
#define EPB 8192       // edges per block in hist/scatter kernels
#define NHB (NBUCK * NBUCK)
#define K2CHUNK 38     // 1024*38 = 38912 >= NHB
#define LPAD 132       // gemm LDS repack row stride (ushorts)

typedef unsigned int uint;
typedef unsigned short ushort;
typedef __attribute__((ext_vector_type(8))) short bf16x8;
typedef __attribute__((ext_vector_type(4))) float f32x4;

__device__ __forceinline__ ushort bf16rn(float f) {
    uint u = __float_as_uint(f);
    u += 0x7fffu + ((u >> 16) & 1u);
    return (ushort)(u >> 16);
}
__device__ __forceinline__ float bflo(uint u) { return __uint_as_float(u << 16); }
__device__ __forceinline__ float bfhi(uint u) { return __uint_as_float(u & 0xffff0000u); }

// ---------------------------------------------------------------------------
// CSR build via two-level bucket sort -> PADDED per-node edge lists:
// node n's edges live at peidx[prow[n] .. prow[n]+16*ceil(deg/16)), padding
// slots are 0 (valid row id; masked off in agg). deg[n] holds the true count.
// ---------------------------------------------------------------------------

__global__ __launch_bounds__(256) void hist_kernel(const int* __restrict__ dst,
                                                   int* __restrict__ ghist) {
    __shared__ int hist[NBUCK];
    int b = blockIdx.x, t = threadIdx.x;
    for (int i = t; i < NBUCK; i += 256) hist[i] = 0;
    __syncthreads();
    int e0 = b * EPB;
    for (int i = 0; i < EPB; i += 256) {
        int e = e0 + i + t;
        if (e < N_EDGES) atomicAdd(&hist[dst[e] >> BSH], 1);
    }
    __syncthreads();
    for (int i = t; i < NBUCK; i += 256) ghist[i * NBUCK + b] = hist[i];
}

// Single block (1024 thr): exclusive scan of NHB ints in-place + bucket bases.
// No integer mod in the hot loop (tracked next-multiple instead).
__global__ __launch_bounds__(1024) void scan_hist_kernel(int* __restrict__ ghist,
                                                         int* __restrict__ gbb) {
    __shared__ int tsum[1024];
    int t = threadIdx.x;
    int base = t * K2CHUNK;
    int s = 0;
    for (int i = 0; i < K2CHUNK; ++i) {
        int idx = base + i;
        if (idx < NHB) s += ghist[idx];
    }
    tsum[t] = s;
    __syncthreads();
    for (int off = 1; off < 1024; off <<= 1) {
        int v = (t >= off) ? tsum[t - off] : 0;
        __syncthreads();
        tsum[t] += v;
        __syncthreads();
    }
    int excl = (t > 0) ? tsum[t - 1] : 0;
    int bidx = (base + NBUCK - 1) / NBUCK;     // one division per thread
    int nextm = bidx * NBUCK;
    for (int i = 0; i < K2CHUNK; ++i) {
        int idx = base + i;
        if (idx < NHB) {
            int v = ghist[idx];
            ghist[idx] = excl;
            if (idx == nextm) { gbb[bidx] = excl; ++bidx; nextm += NBUCK; }
            excl += v;
        }
    }
    if (t == 0) gbb[NBUCK] = N_EDGES;
}

__global__ __launch_bounds__(256) void scatter_kernel(const int* __restrict__ src,
                                                      const int* __restrict__ dst,
                                                      const int* __restrict__ ghist,
                                                      uint* __restrict__ scat) {
    __shared__ int base[NBUCK];
    __shared__ int fill[NBUCK];
    int b = blockIdx.x, t = threadIdx.x;
    for (int i = t; i < NBUCK; i += 256) { base[i] = ghist[i * NBUCK + b]; fill[i] = 0; }
    __syncthreads();
    int e0 = b * EPB;
    for (int i = 0; i < EPB; i += 256) {
        int e = e0 + i + t;
        if (e < N_EDGES) {
            int d = dst[e];
            int sv = src[e];
            int bk = d >> BSH;
            int lp = atomicAdd(&fill[bk], 1);
            scat[base[bk] + lp] = (uint)sv | ((uint)(d & 511) << 17);
        }
    }
}

// One block per bucket -> padded local CSR. Bucket b's padded region starts at
// gbb[b] + b*8192 (per-node pad <= 15, 512 nodes -> slack < 8192).
__global__ __launch_bounds__(256) void bucket_csr_kernel(const uint* __restrict__ scat,
                                                         const int* __restrict__ gbb,
                                                         int* __restrict__ prow,
                                                         int* __restrict__ deg,
                                                         int* __restrict__ peidx) {
    __shared__ int cnt[512], fl[512], pref[512];
    __shared__ int ts[256];
    __shared__ int tot_s;
    int b = blockIdx.x, t = threadIdx.x;
    int beg = gbb[b], end = gbb[b + 1];
    int pb = beg + b * 8192;
    cnt[t] = 0; cnt[t + 256] = 0;
    __syncthreads();
    for (int i = beg + t; i < end; i += 256)
        atomicAdd(&cnt[scat[i] >> 17], 1);
    __syncthreads();
    int c0 = cnt[2 * t], c1 = cnt[2 * t + 1];
    int p0 = (c0 + 15) & ~15, p1 = (c1 + 15) & ~15;
    ts[t] = p0 + p1;
    __syncthreads();
    for (int off = 1; off < 256; off <<= 1) {
        int v = (t >= off) ? ts[t - off] : 0;
        __syncthreads();
        ts[t] += v;
        __syncthreads();
    }
    int ex = (t > 0) ? ts[t - 1] : 0;
    pref[2 * t] = ex;
    pref[2 * t + 1] = ex + p0;
    fl[t] = 0; fl[t + 256] = 0;
    if (t == 255) tot_s = ts[255];
    int g0 = b * 512 + 2 * t;
    if (g0 < N_NODES) { prow[g0] = pb + ex; deg[g0] = c0; }
    if (g0 + 1 < N_NODES) { prow[g0 + 1] = pb + ex + p0; deg[g0 + 1] = c1; }
    __syncthreads();
    int tot = tot_s;
    for (int i = t; i < tot; i += 256) peidx[pb + i] = 0;   // padding = node 0
    __syncthreads();
    for (int i = beg + t; i < end; i += 256) {
        uint w = scat[i];
        int nl = (int)(w >> 17);
        int lp = atomicAdd(&fl[nl], 1);
        peidx[pb + pref[nl] + lp] = (int)(w & 0x1FFFFu);
    }
}

// ---------------------------------------------------------------------------
// Prep
// ---------------------------------------------------------------------------
__global__ void prep_weights_kernel(const float* __restrict__ wl, const float* __restrict__ wr,
                                    ushort* __restrict__ Bt, int K) {
    int n = blockIdx.y;
    int k = blockIdx.x * 64 + threadIdx.x;
    if (k < K) {
        float v = (n < HID) ? wl[k * HID + n] : wr[k * HID + (n - HID)];
        Bt[n * K + k] = bf16rn(v);
    }
}

__global__ void bn_prep_kernel(const float* __restrict__ bl, const float* __restrict__ g,
                               const float* __restrict__ be, const float* __restrict__ rm,
                               const float* __restrict__ rv, float* __restrict__ scale,
                               float* __restrict__ shift) {
    int j = threadIdx.x;
    float s = g[j] * rsqrtf(rv[j] + BN_EPS);
    scale[j] = s;
    shift[j] = (bl[j] - rm[j]) * s + be[j];
}

// ---------------------------------------------------------------------------
// GEMM, N-split: grid (782, 2). y=0 computes cols 0..127 (-> tl), y=1 cols
// 128..255 (-> troot). 128 rows/block, wave = 32 rows x 128 cols (2x8 tiles).
// LDS repack epilogue -> coalesced 256B row stores.
// ---------------------------------------------------------------------------
template <int K, bool AFP32>
__global__ __launch_bounds__(256) void gemm_kernel(const void* __restrict__ A_,
                                                   const ushort* __restrict__ Bt,
                                                   ushort* __restrict__ tl,
                                                   ushort* __restrict__ troot) {
    __shared__ ushort lds[4][16][LPAD];
    const int lane = threadIdx.x & 63;
    const int wv = threadIdx.x >> 6;
    const int col = lane & 15;
    const int kq = (lane >> 4) * 8;
    const int m0 = blockIdx.x * 128 + wv * 32 + col;
    const int nc0 = blockIdx.y * 128;           // col-half base in Bt
    ushort* outp = blockIdx.y ? troot : tl;
    f32x4 acc[2][8];
#pragma unroll
    for (int a = 0; a < 2; ++a)
#pragma unroll
        for (int t = 0; t < 8; ++t) acc[a][t] = (f32x4){0.f, 0.f, 0.f, 0.f};

#pragma unroll
    for (int k0 = 0; k0 < K; k0 += 32) {
        int kk = k0 + kq;
        bf16x8 a0, a1;
        if (AFP32) {
            const float* A = (const float*)A_;
            float4 z = make_float4(0.f, 0.f, 0.f, 0.f);
            float4 f00 = z, f01 = z, f10 = z, f11 = z;
            if (m0 < N_NODES) {
                f00 = *(const float4*)(A + (size_t)m0 * K + kk);
                f01 = *(const float4*)(A + (size_t)m0 * K + kk + 4);
            }
            if (m0 + 16 < N_NODES) {
                f10 = *(const float4*)(A + (size_t)(m0 + 16) * K + kk);
                f11 = *(const float4*)(A + (size_t)(m0 + 16) * K + kk + 4);
            }
            a0[0] = (short)bf16rn(f00.x); a0[1] = (short)bf16rn(f00.y);
            a0[2] = (short)bf16rn(f00.z); a0[3] = (short)bf16rn(f00.w);
            a0[4] = (short)bf16rn(f01.x); a0[5] = (short)bf16rn(f01.y);
            a0[6] = (short)bf16rn(f01.z); a0[7] = (short)bf16rn(f01.w);
            a1[0] = (short)bf16rn(f10.x); a1[1] = (short)bf16rn(f10.y);
            a1[2] = (short)bf16rn(f10.z); a1[3] = (short)bf16rn(f10.w);
            a1[4] = (short)bf16rn(f11.x); a1[5] = (short)bf16rn(f11.y);
            a1[6] = (short)bf16rn(f11.z); a1[7] = (short)bf16rn(f11.w);
        } else {
            const ushort* A = (const ushort*)A_;
            a0 = *(const bf16x8*)(A + (size_t)m0 * K + kk);
            a1 = *(const bf16x8*)(A + (size_t)(m0 + 16) * K + kk);
        }
#pragma unroll
        for (int t = 0; t < 8; ++t) {
            bf16x8 bfr = *(const bf16x8*)(Bt + (size_t)(nc0 + t * 16 + col) * K + kk);
            acc[0][t] = __builtin_amdgcn_mfma_f32_16x16x32_bf16(a0, bfr, acc[0][t], 0, 0, 0);
            acc[1][t] = __builtin_amdgcn_mfma_f32_16x16x32_bf16(a1, bfr, acc[1][t], 0, 0, 0);
        }
    }

    const int quad = lane >> 4;
#pragma unroll
    for (int mt = 0; mt < 2; ++mt) {
#pragma unroll
        for (int tt = 0; tt < 8; ++tt)
#pragma unroll
            for (int r = 0; r < 4; ++r)
                lds[wv][quad * 4 + r][tt * 16 + col] = bf16rn(acc[mt][tt][r]);
        int mbase = blockIdx.x * 128 + wv * 32 + mt * 16;
#pragma unroll
        for (int i = 0; i < 4; ++i) {
            int lin = i * 64 + lane;
            int row = lin >> 4;      // 4 rows per instr (16 lanes x 16B = 128 cols)
            int c16 = lin & 15;
            bf16x8 v = *(const bf16x8*)&lds[wv][row][c16 * 8];
            *(bf16x8*)(outp + (size_t)(mbase + row) * HID + c16 * 8) = v;
        }
    }
}

// ---------------------------------------------------------------------------
// Aggregation + BN + ReLU (+ fused final linear).
// Wave = 4 nodes, one per 16-lane group. Each gather instruction fetches 16B
// per lane with per-lane addresses -> 4 edge rows (1024B) per vmem instr, 4x
// the in-flight bytes per vmcnt slot vs the one-row-per-instr scheme.
// ---------------------------------------------------------------------------
template <bool FINAL>
__global__ __launch_bounds__(256) void agg_kernel(
    const ushort* __restrict__ tl_, const ushort* __restrict__ troot_,
    const int* __restrict__ prow, const int* __restrict__ deg_,
    const int* __restrict__ peidx,
    const float* __restrict__ bnscale, const float* __restrict__ bnshift,
    const float* __restrict__ linw, const float* __restrict__ linb,
    ushort* __restrict__ hout, float* __restrict__ out) {
    const int lane = threadIdx.x & 63;
    const int wvg = (blockIdx.x * 256 + (int)threadIdx.x) >> 6;
    const int g = lane >> 4;          // group 0..3 -> node
    const int s = lane & 15;          // feat slice: feats s*8 .. s*8+7
    const int n = wvg * 4 + g;
    const int nn = (n < N_NODES) ? n : (N_NODES - 1);

    // Per-lane BN params for this slice.
    float4 sc0 = *(const float4*)(bnscale + s * 8);
    float4 sc1 = *(const float4*)(bnscale + s * 8 + 4);
    float4 sh0 = *(const float4*)(bnshift + s * 8);
    float4 sh1 = *(const float4*)(bnshift + s * 8 + 4);

    int pbeg = prow[nn];
    int dg = (n < N_NODES) ? deg_[nn] : 0;
    int myb = (dg + 15) >> 4;         // batches of 16 edges

    float acc[8];
#pragma unroll
    for (int i = 0; i < 8; ++i) acc[i] = 0.f;

    const int gsel = (lane & 48) << 2;   // bpermute byte-addr base of my group

    for (int b = 0;; ++b) {
        bool act = b < myb;
        if (!__any(act)) break;
        int base = act ? (pbeg + b * 16) : 0;
        int idx = peidx[base + s];        // 16 ids for my group's next batch
#pragma unroll
        for (int jj = 0; jj < 16; ++jj) {
            int src = __builtin_amdgcn_ds_bpermute(gsel | (jj << 2), idx);
            bool val = (b * 16 + jj) < dg;
            src = val ? src : 0;          // keep row 0 hot for masked steps
            uint4 v = *(const uint4*)(tl_ + (size_t)src * HID + s * 8);
            float m = val ? 1.f : 0.f;
            acc[0] = fmaf(m, bflo(v.x), acc[0]);
            acc[1] = fmaf(m, bfhi(v.x), acc[1]);
            acc[2] = fmaf(m, bflo(v.y), acc[2]);
            acc[3] = fmaf(m, bfhi(v.y), acc[3]);
            acc[4] = fmaf(m, bflo(v.z), acc[4]);
            acc[5] = fmaf(m, bfhi(v.z), acc[5]);
            acc[6] = fmaf(m, bflo(v.w), acc[6]);
            acc[7] = fmaf(m, bfhi(v.w), acc[7]);
        }
    }

    float inv = 1.0f / (float)((dg > 0) ? dg : 1);
    uint4 rv = *(const uint4*)(troot_ + (size_t)nn * HID + s * 8);
    float o[8];
    o[0] = fmaxf(fmaf(fmaf(acc[0], inv, bflo(rv.x)), sc0.x, sh0.x), 0.f);
    o[1] = fmaxf(fmaf(fmaf(acc[1], inv, bfhi(rv.x)), sc0.y, sh0.y), 0.f);
    o[2] = fmaxf(fmaf(fmaf(acc[2], inv, bflo(rv.y)), sc0.z, sh0.z), 0.f);
    o[3] = fmaxf(fmaf(fmaf(acc[3], inv, bfhi(rv.y)), sc0.w, sh0.w), 0.f);
    o[4] = fmaxf(fmaf(fmaf(acc[4], inv, bflo(rv.z)), sc1.x, sh1.x), 0.f);
    o[5] = fmaxf(fmaf(fmaf(acc[5], inv, bfhi(rv.z)), sc1.y, sh1.y), 0.f);
    o[6] = fmaxf(fmaf(fmaf(acc[6], inv, bflo(rv.w)), sc1.z, sh1.z), 0.f);
    o[7] = fmaxf(fmaf(fmaf(acc[7], inv, bfhi(rv.w)), sc1.w, sh1.w), 0.f);

    if (FINAL) {
        float4 w0 = *(const float4*)(linw + s * 8);
        float4 w1 = *(const float4*)(linw + s * 8 + 4);
        float p = o[0] * w0.x + o[1] * w0.y + o[2] * w0.z + o[3] * w0.w +
                  o[4] * w1.x + o[5] * w1.y + o[6] * w1.z + o[7] * w1.w;
#pragma unroll
        for (int off = 1; off < 16; off <<= 1) p += __shfl_xor(p, off);
        if (s == 0 && n < N_NODES) out[n] = p + linb[0];
    } else {
        uint4 pk;
        pk.x = (uint)bf16rn(o[0]) | ((uint)bf16rn(o[1]) << 16);
        pk.y = (uint)bf16rn(o[2]) | ((uint)bf16rn(o[3]) << 16);
        pk.z = (uint)bf16rn(o[4]) | ((uint)bf16rn(o[5]) << 16);
        pk.w = (uint)bf16rn(o[6]) | ((uint)bf16rn(o[7]) << 16);
        if (n < N_NODES) *(uint4*)(hout + (size_t)n * HID + s * 8) = pk;
    }
}

// ---------------------------------------------------------------------------

extern "C" void kernel_launch(void* const* d_in, const int* in_sizes, int n_in,
                              void* d_out, int out_size, void* d_ws, size_t ws_size,
                              hipStream_t stream) {
    const float* x    = (const float*)d_in[0];
    const int*   ei   = (const int*)d_in[1];
    const int*   esrc = ei;
    const int*   edst = ei + N_EDGES;
    const float* wl[3]; const float* wr[3]; const float* bl[3];
    const float* g[3];  const float* be[3]; const float* rm[3]; const float* rv[3];
    for (int i = 0; i < 3; ++i) {
        wl[i] = (const float*)d_in[2 + 7 * i];
        wr[i] = (const float*)d_in[3 + 7 * i];
        bl[i] = (const float*)d_in[4 + 7 * i];
        g[i]  = (const float*)d_in[5 + 7 * i];
        be[i] = (const float*)d_in[6 + 7 * i];
        rm[i] = (const float*)d_in[7 + 7 * i];
        rv[i] = (const float*)d_in[8 + 7 * i];
    }
    const float* lin_w = (const float*)d_in[23];
    const float* lin_b = (const float*)d_in[24];
    float* out = (float*)d_out;

    // Workspace carve-up (~98 MB total).
    char* ws = (char*)d_ws;
    size_t off = 0;
    auto carve = [&](size_t bytes) -> void* {
        void* p = ws + off;
        off += (bytes + 255) & ~(size_t)255;
        return p;
    };
    int*    prow   = (int*)carve((size_t)(N_NODES + 8) * sizeof(int));
    int*    deg    = (int*)carve((size_t)(N_NODES + 8) * sizeof(int));
    int*    peidx  = (int*)carve((size_t)3210000 * sizeof(int));   // padded CSR
    uint*   scat   = (uint*)carve((size_t)N_EDGES * sizeof(uint));
    int*    ghist  = (int*)carve((size_t)NHB * sizeof(int));
    int*    gbb    = (int*)carve((NBUCK + 4) * sizeof(int));
    ushort* tl     = (ushort*)carve((size_t)M_PAD * HID * sizeof(ushort));
    ushort* troot  = (ushort*)carve((size_t)M_PAD * HID * sizeof(ushort));
    ushort* h      = (ushort*)carve((size_t)M_PAD * HID * sizeof(ushort));
    ushort* Bt0    = (ushort*)carve(256 * IN_DIM * sizeof(ushort));
    ushort* Bt1    = (ushort*)carve(256 * HID * sizeof(ushort));
    ushort* Bt2    = (ushort*)carve(256 * HID * sizeof(ushort));
    float*  bnsc   = (float*)carve(3 * HID * sizeof(float));
    float*  bnsh   = (float*)carve(3 * HID * sizeof(float));
    (void)ws_size; (void)n_in; (void)in_sizes; (void)out_size;

    hist_kernel<<<NBUCK, 256, 0, stream>>>(edst, ghist);
    scan_hist_kernel<<<1, 1024, 0, stream>>>(ghist, gbb);
    scatter_kernel<<<NBUCK, 256, 0, stream>>>(esrc, edst, ghist, scat);
    bucket_csr_kernel<<<NBUCK, 256, 0, stream>>>(scat, gbb, prow, deg, peidx);

    prep_weights_kernel<<<dim3((IN_DIM + 63) / 64, 256), 64, 0, stream>>>(wl[0], wr[0], Bt0, IN_DIM);
    prep_weights_kernel<<<dim3((HID + 63) / 64, 256), 64, 0, stream>>>(wl[1], wr[1], Bt1, HID);
    prep_weights_kernel<<<dim3((HID + 63) / 64, 256), 64, 0, stream>>>(wl[2], wr[2], Bt2, HID);
    bn_prep_kernel<<<1, HID, 0, stream>>>(bl[0], g[0], be[0], rm[0], rv[0], bnsc, bnsh);
    bn_prep_kernel<<<1, HID, 0, stream>>>(bl[1], g[1], be[1], rm[1], rv[1], bnsc + HID, bnsh + HID);
    bn_prep_kernel<<<1, HID, 0, stream>>>(bl[2], g[2], be[2], rm[2], rv[2], bnsc + 2 * HID, bnsh + 2 * HID);

    const dim3 GEMM_GRID(M_PAD / 128, 2);       // 782 x 2
    const int AGG_GRID = (N_NODES + 15) / 16;   // 4 nodes/wave, 4 waves/block

    gemm_kernel<IN_DIM, true><<<GEMM_GRID, 256, 0, stream>>>(x, Bt0, tl, troot);
    agg_kernel<false><<<AGG_GRID, 256, 0, stream>>>(tl, troot, prow, deg, peidx, bnsc, bnsh,
                                                    nullptr, nullptr, h, nullptr);
    gemm_kernel<HID, false><<<GEMM_GRID, 256, 0, stream>>>(h, Bt1, tl, troot);
    agg_kernel<false><<<AGG_GRID, 256, 0, stream>>>(tl, troot, prow, deg, peidx, bnsc + HID, bnsh + HID,
                                                    nullptr, nullptr, h, nullptr);
    gemm_kernel<HID, false><<<GEMM_GRID, 256, 0, stream>>>(h, Bt2, tl, troot);
    agg_kernel<true><<<AGG_GRID, 256, 0, stream>>>(tl, troot, prow, deg, peidx, bnsc + 2 * HID, bnsh + 2 * HID,
                                                   lin_w, lin_b, nullptr, out);
}

// Round 6
// 507.624 us; speedup vs baseline: 1.5110x; 1.1352x over previous
//
#include <hip/hip_runtime.h>

#define N_NODES 100000
#define N_EDGES 1600000
#define IN_DIM 160
#define HID 128
#define BN_EPS 1e-5f

#define M_PAD 100096   // 782 * 128 rows (GEMM block = 128 rows)
#define NBUCK 196      // 512-node buckets (196*512 = 100352 >= N_NODES)
#define BSH 9
#define EPB 8192       // edges per block in hist/scatter kernels
#define NHB (NBUCK * NBUCK)   // 38416, divisible by 4
#define NSB 38         // scan blocks: 38*1024 = 38912 >= NHB
#define LPAD 132       // gemm LDS repack row stride (ushorts)

typedef unsigned int uint;
typedef unsigned short ushort;
typedef __attribute__((ext_vector_type(8))) short bf16x8;
typedef __attribute__((ext_vector_type(4))) float f32x4;

__device__ __forceinline__ ushort bf16rn(float f) {
    uint u = __float_as_uint(f);
    u += 0x7fffu + ((u >> 16) & 1u);
    return (ushort)(u >> 16);
}
__device__ __forceinline__ float bflo(uint u) { return __uint_as_float(u << 16); }
__device__ __forceinline__ float bfhi(uint u) { return __uint_as_float(u & 0xffff0000u); }

// ---------------------------------------------------------------------------
// CSR build via two-level bucket sort -> PADDED per-node edge lists.
// ---------------------------------------------------------------------------

__global__ __launch_bounds__(256) void hist_kernel(const int* __restrict__ dst,
                                                   int* __restrict__ ghist) {
    __shared__ int hist[NBUCK];
    int b = blockIdx.x, t = threadIdx.x;
    for (int i = t; i < NBUCK; i += 256) hist[i] = 0;
    __syncthreads();
    int e0 = b * EPB;
    for (int i = 0; i < EPB; i += 256) {
        int e = e0 + i + t;
        if (e < N_EDGES) atomicAdd(&hist[dst[e] >> BSH], 1);
    }
    __syncthreads();
    for (int i = t; i < NBUCK; i += 256) ghist[i * NBUCK + b] = hist[i];
}

// Multi-block scan of ghist[NHB], step 1: per-block (1024-int) sums.
__global__ __launch_bounds__(256) void scan1_kernel(const int* __restrict__ ghist,
                                                    int* __restrict__ bsum) {
    __shared__ int wsum[4];
    int b = blockIdx.x, t = threadIdx.x;
    int i4 = b * 256 + t;
    int4 v = (i4 * 4 < NHB) ? ((const int4*)ghist)[i4] : make_int4(0, 0, 0, 0);
    int s = v.x + v.y + v.z + v.w;
#pragma unroll
    for (int off = 32; off; off >>= 1) s += __shfl_down(s, off);
    if ((t & 63) == 0) wsum[t >> 6] = s;
    __syncthreads();
    if (t == 0) bsum[b] = wsum[0] + wsum[1] + wsum[2] + wsum[3];
}

// Step 2: single wave exclusive-scans the NSB partials.
__global__ void scan2_kernel(const int* __restrict__ bsum, int* __restrict__ boff,
                             int* __restrict__ gbb) {
    int lane = threadIdx.x;
    int v = (lane < NSB) ? bsum[lane] : 0;
    int s = v;
#pragma unroll
    for (int off = 1; off <= 32; off <<= 1) {
        int t2 = __shfl_up(s, off);
        if (lane >= off) s += t2;
    }
    if (lane < NSB) boff[lane] = s - v;
    if (lane == 0) gbb[NBUCK] = N_EDGES;
}

// Step 3: final exclusive scan write-back + bucket bases (idx % NBUCK == 0
// only occurs in the .x slot since NBUCK % 4 == 0).
__global__ __launch_bounds__(256) void scan3_kernel(int* __restrict__ ghist,
                                                    const int* __restrict__ boff,
                                                    int* __restrict__ gbb) {
    __shared__ int ts[256];
    int b = blockIdx.x, t = threadIdx.x;
    int i4 = b * 256 + t;
    bool ok = (i4 * 4) < NHB;
    int4 v = ok ? ((const int4*)ghist)[i4] : make_int4(0, 0, 0, 0);
    int s = v.x + v.y + v.z + v.w;
    ts[t] = s;
    __syncthreads();
    for (int off = 1; off < 256; off <<= 1) {
        int a = (t >= off) ? ts[t - off] : 0;
        __syncthreads();
        ts[t] += a;
        __syncthreads();
    }
    int excl = boff[b] + ((t > 0) ? ts[t - 1] : 0);
    if (ok) {
        int idx = i4 * 4;
        int4 w;
        w.x = excl;
        w.y = excl + v.x;
        w.z = excl + v.x + v.y;
        w.w = excl + v.x + v.y + v.z;
        ((int4*)ghist)[i4] = w;
        if (idx % NBUCK == 0) gbb[idx / NBUCK] = w.x;
    }
}

__global__ __launch_bounds__(256) void scatter_kernel(const int* __restrict__ src,
                                                      const int* __restrict__ dst,
                                                      const int* __restrict__ ghist,
                                                      uint* __restrict__ scat) {
    __shared__ int base[NBUCK];
    __shared__ int fill[NBUCK];
    int b = blockIdx.x, t = threadIdx.x;
    for (int i = t; i < NBUCK; i += 256) { base[i] = ghist[i * NBUCK + b]; fill[i] = 0; }
    __syncthreads();
    int e0 = b * EPB;
    for (int i = 0; i < EPB; i += 256) {
        int e = e0 + i + t;
        if (e < N_EDGES) {
            int d = dst[e];
            int sv = src[e];
            int bk = d >> BSH;
            int lp = atomicAdd(&fill[bk], 1);
            scat[base[bk] + lp] = (uint)sv | ((uint)(d & 511) << 17);
        }
    }
}

// One block per bucket -> padded local CSR. Bucket b's padded region starts at
// gbb[b] + b*8192 (per-node pad <= 15, 512 nodes -> slack < 8192).
__global__ __launch_bounds__(256) void bucket_csr_kernel(const uint* __restrict__ scat,
                                                         const int* __restrict__ gbb,
                                                         int* __restrict__ prow,
                                                         int* __restrict__ deg,
                                                         int* __restrict__ peidx) {
    __shared__ int cnt[512], fl[512], pref[512];
    __shared__ int ts[256];
    __shared__ int tot_s;
    int b = blockIdx.x, t = threadIdx.x;
    int beg = gbb[b], end = gbb[b + 1];
    int pb = beg + b * 8192;
    cnt[t] = 0; cnt[t + 256] = 0;
    __syncthreads();
    for (int i = beg + t; i < end; i += 256)
        atomicAdd(&cnt[scat[i] >> 17], 1);
    __syncthreads();
    int c0 = cnt[2 * t], c1 = cnt[2 * t + 1];
    int p0 = (c0 + 15) & ~15, p1 = (c1 + 15) & ~15;
    ts[t] = p0 + p1;
    __syncthreads();
    for (int off = 1; off < 256; off <<= 1) {
        int v = (t >= off) ? ts[t - off] : 0;
        __syncthreads();
        ts[t] += v;
        __syncthreads();
    }
    int ex = (t > 0) ? ts[t - 1] : 0;
    pref[2 * t] = ex;
    pref[2 * t + 1] = ex + p0;
    fl[t] = 0; fl[t + 256] = 0;
    if (t == 255) tot_s = ts[255];
    int g0 = b * 512 + 2 * t;
    if (g0 < N_NODES) { prow[g0] = pb + ex; deg[g0] = c0; }
    if (g0 + 1 < N_NODES) { prow[g0 + 1] = pb + ex + p0; deg[g0 + 1] = c1; }
    __syncthreads();
    int tot = tot_s;
    for (int i = t; i < tot; i += 256) peidx[pb + i] = 0;   // padding = node 0
    __syncthreads();
    for (int i = beg + t; i < end; i += 256) {
        uint w = scat[i];
        int nl = (int)(w >> 17);
        int lp = atomicAdd(&fl[nl], 1);
        peidx[pb + pref[nl] + lp] = (int)(w & 0x1FFFFu);
    }
}

// ---------------------------------------------------------------------------
// Prep
// ---------------------------------------------------------------------------
__global__ void prep_weights_kernel(const float* __restrict__ wl, const float* __restrict__ wr,
                                    ushort* __restrict__ Bt, int K) {
    int n = blockIdx.y;
    int k = blockIdx.x * 64 + threadIdx.x;
    if (k < K) {
        float v = (n < HID) ? wl[k * HID + n] : wr[k * HID + (n - HID)];
        Bt[n * K + k] = bf16rn(v);
    }
}

__global__ void bn_prep_kernel(const float* __restrict__ bl, const float* __restrict__ g,
                               const float* __restrict__ be, const float* __restrict__ rm,
                               const float* __restrict__ rv, float* __restrict__ scale,
                               float* __restrict__ shift) {
    int j = threadIdx.x;
    float s = g[j] * rsqrtf(rv[j] + BN_EPS);
    scale[j] = s;
    shift[j] = (bl[j] - rm[j]) * s + be[j];
}

// ---------------------------------------------------------------------------
// GEMM, N-split: grid (782, 2). y=0 -> tl (cols 0..127), y=1 -> troot.
// ---------------------------------------------------------------------------
template <int K, bool AFP32>
__global__ __launch_bounds__(256) void gemm_kernel(const void* __restrict__ A_,
                                                   const ushort* __restrict__ Bt,
                                                   ushort* __restrict__ tl,
                                                   ushort* __restrict__ troot) {
    __shared__ ushort lds[4][16][LPAD];
    const int lane = threadIdx.x & 63;
    const int wv = threadIdx.x >> 6;
    const int col = lane & 15;
    const int kq = (lane >> 4) * 8;
    const int m0 = blockIdx.x * 128 + wv * 32 + col;
    const int nc0 = blockIdx.y * 128;           // col-half base in Bt
    ushort* outp = blockIdx.y ? troot : tl;
    f32x4 acc[2][8];
#pragma unroll
    for (int a = 0; a < 2; ++a)
#pragma unroll
        for (int t = 0; t < 8; ++t) acc[a][t] = (f32x4){0.f, 0.f, 0.f, 0.f};

#pragma unroll
    for (int k0 = 0; k0 < K; k0 += 32) {
        int kk = k0 + kq;
        bf16x8 a0, a1;
        if (AFP32) {
            const float* A = (const float*)A_;
            float4 z = make_float4(0.f, 0.f, 0.f, 0.f);
            float4 f00 = z, f01 = z, f10 = z, f11 = z;
            if (m0 < N_NODES) {
                f00 = *(const float4*)(A + (size_t)m0 * K + kk);
                f01 = *(const float4*)(A + (size_t)m0 * K + kk + 4);
            }
            if (m0 + 16 < N_NODES) {
                f10 = *(const float4*)(A + (size_t)(m0 + 16) * K + kk);
                f11 = *(const float4*)(A + (size_t)(m0 + 16) * K + kk + 4);
            }
            a0[0] = (short)bf16rn(f00.x); a0[1] = (short)bf16rn(f00.y);
            a0[2] = (short)bf16rn(f00.z); a0[3] = (short)bf16rn(f00.w);
            a0[4] = (short)bf16rn(f01.x); a0[5] = (short)bf16rn(f01.y);
            a0[6] = (short)bf16rn(f01.z); a0[7] = (short)bf16rn(f01.w);
            a1[0] = (short)bf16rn(f10.x); a1[1] = (short)bf16rn(f10.y);
            a1[2] = (short)bf16rn(f10.z); a1[3] = (short)bf16rn(f10.w);
            a1[4] = (short)bf16rn(f11.x); a1[5] = (short)bf16rn(f11.y);
            a1[6] = (short)bf16rn(f11.z); a1[7] = (short)bf16rn(f11.w);
        } else {
            const ushort* A = (const ushort*)A_;
            a0 = *(const bf16x8*)(A + (size_t)m0 * K + kk);
            a1 = *(const bf16x8*)(A + (size_t)(m0 + 16) * K + kk);
        }
#pragma unroll
        for (int t = 0; t < 8; ++t) {
            bf16x8 bfr = *(const bf16x8*)(Bt + (size_t)(nc0 + t * 16 + col) * K + kk);
            acc[0][t] = __builtin_amdgcn_mfma_f32_16x16x32_bf16(a0, bfr, acc[0][t], 0, 0, 0);
            acc[1][t] = __builtin_amdgcn_mfma_f32_16x16x32_bf16(a1, bfr, acc[1][t], 0, 0, 0);
        }
    }

    const int quad = lane >> 4;
#pragma unroll
    for (int mt = 0; mt < 2; ++mt) {
#pragma unroll
        for (int tt = 0; tt < 8; ++tt)
#pragma unroll
            for (int r = 0; r < 4; ++r)
                lds[wv][quad * 4 + r][tt * 16 + col] = bf16rn(acc[mt][tt][r]);
        int mbase = blockIdx.x * 128 + wv * 32 + mt * 16;
#pragma unroll
        for (int i = 0; i < 4; ++i) {
            int lin = i * 64 + lane;
            int row = lin >> 4;      // 4 rows per instr (16 lanes x 16B = 128 cols)
            int c16 = lin & 15;
            bf16x8 v = *(const bf16x8*)&lds[wv][row][c16 * 8];
            *(bf16x8*)(outp + (size_t)(mbase + row) * HID + c16 * 8) = v;
        }
    }
}

// ---------------------------------------------------------------------------
// Aggregation + BN + ReLU (+ fused final linear).
// Wave = 4 nodes, one per 16-lane group; per-lane addresses -> 4 edge rows
// (1024B) per vmem instruction.
// ---------------------------------------------------------------------------
template <bool FINAL>
__global__ __launch_bounds__(256) void agg_kernel(
    const ushort* __restrict__ tl_, const ushort* __restrict__ troot_,
    const int* __restrict__ prow, const int* __restrict__ deg_,
    const int* __restrict__ peidx,
    const float* __restrict__ bnscale, const float* __restrict__ bnshift,
    const float* __restrict__ linw, const float* __restrict__ linb,
    ushort* __restrict__ hout, float* __restrict__ out) {
    const int lane = threadIdx.x & 63;
    const int wvg = (blockIdx.x * 256 + (int)threadIdx.x) >> 6;
    const int g = lane >> 4;          // group 0..3 -> node
    const int s = lane & 15;          // feat slice: feats s*8 .. s*8+7
    const int n = wvg * 4 + g;
    const int nn = (n < N_NODES) ? n : (N_NODES - 1);

    float4 sc0 = *(const float4*)(bnscale + s * 8);
    float4 sc1 = *(const float4*)(bnscale + s * 8 + 4);
    float4 sh0 = *(const float4*)(bnshift + s * 8);
    float4 sh1 = *(const float4*)(bnshift + s * 8 + 4);

    int pbeg = prow[nn];
    int dg = (n < N_NODES) ? deg_[nn] : 0;
    int myb = (dg + 15) >> 4;         // batches of 16 edges

    float acc[8];
#pragma unroll
    for (int i = 0; i < 8; ++i) acc[i] = 0.f;

    const int gsel = (lane & 48) << 2;   // bpermute byte-addr base of my group

    for (int b = 0;; ++b) {
        bool act = b < myb;
        if (!__any(act)) break;
        int base = act ? (pbeg + b * 16) : 0;
        int idx = peidx[base + s];        // 16 ids for my group's next batch
#pragma unroll
        for (int jj = 0; jj < 16; ++jj) {
            int src = __builtin_amdgcn_ds_bpermute(gsel | (jj << 2), idx);
            bool val = (b * 16 + jj) < dg;
            src = val ? src : 0;          // keep row 0 hot for masked steps
            uint4 v = *(const uint4*)(tl_ + (size_t)src * HID + s * 8);
            float m = val ? 1.f : 0.f;
            acc[0] = fmaf(m, bflo(v.x), acc[0]);
            acc[1] = fmaf(m, bfhi(v.x), acc[1]);
            acc[2] = fmaf(m, bflo(v.y), acc[2]);
            acc[3] = fmaf(m, bfhi(v.y), acc[3]);
            acc[4] = fmaf(m, bflo(v.z), acc[4]);
            acc[5] = fmaf(m, bfhi(v.z), acc[5]);
            acc[6] = fmaf(m, bflo(v.w), acc[6]);
            acc[7] = fmaf(m, bfhi(v.w), acc[7]);
        }
    }

    float inv = 1.0f / (float)((dg > 0) ? dg : 1);
    uint4 rv = *(const uint4*)(troot_ + (size_t)nn * HID + s * 8);
    float o[8];
    o[0] = fmaxf(fmaf(fmaf(acc[0], inv, bflo(rv.x)), sc0.x, sh0.x), 0.f);
    o[1] = fmaxf(fmaf(fmaf(acc[1], inv, bfhi(rv.x)), sc0.y, sh0.y), 0.f);
    o[2] = fmaxf(fmaf(fmaf(acc[2], inv, bflo(rv.y)), sc0.z, sh0.z), 0.f);
    o[3] = fmaxf(fmaf(fmaf(acc[3], inv, bfhi(rv.y)), sc0.w, sh0.w), 0.f);
    o[4] = fmaxf(fmaf(fmaf(acc[4], inv, bflo(rv.z)), sc1.x, sh1.x), 0.f);
    o[5] = fmaxf(fmaf(fmaf(acc[5], inv, bfhi(rv.z)), sc1.y, sh1.y), 0.f);
    o[6] = fmaxf(fmaf(fmaf(acc[6], inv, bflo(rv.w)), sc1.z, sh1.z), 0.f);
    o[7] = fmaxf(fmaf(fmaf(acc[7], inv, bfhi(rv.w)), sc1.w, sh1.w), 0.f);

    if (FINAL) {
        float4 w0 = *(const float4*)(linw + s * 8);
        float4 w1 = *(const float4*)(linw + s * 8 + 4);
        float p = o[0] * w0.x + o[1] * w0.y + o[2] * w0.z + o[3] * w0.w +
                  o[4] * w1.x + o[5] * w1.y + o[6] * w1.z + o[7] * w1.w;
#pragma unroll
        for (int off = 1; off < 16; off <<= 1) p += __shfl_xor(p, off);
        if (s == 0 && n < N_NODES) out[n] = p + linb[0];
    } else {
        uint4 pk;
        pk.x = (uint)bf16rn(o[0]) | ((uint)bf16rn(o[1]) << 16);
        pk.y = (uint)bf16rn(o[2]) | ((uint)bf16rn(o[3]) << 16);
        pk.z = (uint)bf16rn(o[4]) | ((uint)bf16rn(o[5]) << 16);
        pk.w = (uint)bf16rn(o[6]) | ((uint)bf16rn(o[7]) << 16);
        if (n < N_NODES) *(uint4*)(hout + (size_t)n * HID + s * 8) = pk;
    }
}

// ---------------------------------------------------------------------------

extern "C" void kernel_launch(void* const* d_in, const int* in_sizes, int n_in,
                              void* d_out, int out_size, void* d_ws, size_t ws_size,
                              hipStream_t stream) {
    const float* x    = (const float*)d_in[0];
    const int*   ei   = (const int*)d_in[1];
    const int*   esrc = ei;
    const int*   edst = ei + N_EDGES;
    const float* wl[3]; const float* wr[3]; const float* bl[3];
    const float* g[3];  const float* be[3]; const float* rm[3]; const float* rv[3];
    for (int i = 0; i < 3; ++i) {
        wl[i] = (const float*)d_in[2 + 7 * i];
        wr[i] = (const float*)d_in[3 + 7 * i];
        bl[i] = (const float*)d_in[4 + 7 * i];
        g[i]  = (const float*)d_in[5 + 7 * i];
        be[i] = (const float*)d_in[6 + 7 * i];
        rm[i] = (const float*)d_in[7 + 7 * i];
        rv[i] = (const float*)d_in[8 + 7 * i];
    }
    const float* lin_w = (const float*)d_in[23];
    const float* lin_b = (const float*)d_in[24];
    float* out = (float*)d_out;

    // Workspace carve-up (~98 MB total).
    char* ws = (char*)d_ws;
    size_t off = 0;
    auto carve = [&](size_t bytes) -> void* {
        void* p = ws + off;
        off += (bytes + 255) & ~(size_t)255;
        return p;
    };
    int*    prow   = (int*)carve((size_t)(N_NODES + 8) * sizeof(int));
    int*    deg    = (int*)carve((size_t)(N_NODES + 8) * sizeof(int));
    int*    peidx  = (int*)carve((size_t)3210000 * sizeof(int));   // padded CSR
    uint*   scat   = (uint*)carve((size_t)N_EDGES * sizeof(uint));
    int*    ghist  = (int*)carve((size_t)(NSB * 1024) * sizeof(int));
    int*    gbb    = (int*)carve((NBUCK + 4) * sizeof(int));
    int*    bsum   = (int*)carve((NSB + 2) * sizeof(int));
    int*    boff   = (int*)carve((NSB + 2) * sizeof(int));
    ushort* tl     = (ushort*)carve((size_t)M_PAD * HID * sizeof(ushort));
    ushort* troot  = (ushort*)carve((size_t)M_PAD * HID * sizeof(ushort));
    ushort* h      = (ushort*)carve((size_t)M_PAD * HID * sizeof(ushort));
    ushort* Bt0    = (ushort*)carve(256 * IN_DIM * sizeof(ushort));
    ushort* Bt1    = (ushort*)carve(256 * HID * sizeof(ushort));
    ushort* Bt2    = (ushort*)carve(256 * HID * sizeof(ushort));
    float*  bnsc   = (float*)carve(3 * HID * sizeof(float));
    float*  bnsh   = (float*)carve(3 * HID * sizeof(float));
    (void)ws_size; (void)n_in; (void)in_sizes; (void)out_size;

    hist_kernel<<<NBUCK, 256, 0, stream>>>(edst, ghist);
    scan1_kernel<<<NSB, 256, 0, stream>>>(ghist, bsum);
    scan2_kernel<<<1, 64, 0, stream>>>(bsum, boff, gbb);
    scan3_kernel<<<NSB, 256, 0, stream>>>(ghist, boff, gbb);
    scatter_kernel<<<NBUCK, 256, 0, stream>>>(esrc, edst, ghist, scat);
    bucket_csr_kernel<<<NBUCK, 256, 0, stream>>>(scat, gbb, prow, deg, peidx);

    prep_weights_kernel<<<dim3((IN_DIM + 63) / 64, 256), 64, 0, stream>>>(wl[0], wr[0], Bt0, IN_DIM);
    prep_weights_kernel<<<dim3((HID + 63) / 64, 256), 64, 0, stream>>>(wl[1], wr[1], Bt1, HID);
    prep_weights_kernel<<<dim3((HID + 63) / 64, 256), 64, 0, stream>>>(wl[2], wr[2], Bt2, HID);
    bn_prep_kernel<<<1, HID, 0, stream>>>(bl[0], g[0], be[0], rm[0], rv[0], bnsc, bnsh);
    bn_prep_kernel<<<1, HID, 0, stream>>>(bl[1], g[1], be[1], rm[1], rv[1], bnsc + HID, bnsh + HID);
    bn_prep_kernel<<<1, HID, 0, stream>>>(bl[2], g[2], be[2], rm[2], rv[2], bnsc + 2 * HID, bnsh + 2 * HID);

    const dim3 GEMM_GRID(M_PAD / 128, 2);       // 782 x 2
    const int AGG_GRID = (N_NODES + 15) / 16;   // 4 nodes/wave, 4 waves/block

    gemm_kernel<IN_DIM, true><<<GEMM_GRID, 256, 0, stream>>>(x, Bt0, tl, troot);
    agg_kernel<false><<<AGG_GRID, 256, 0, stream>>>(tl, troot, prow, deg, peidx, bnsc, bnsh,
                                                    nullptr, nullptr, h, nullptr);
    gemm_kernel<HID, false><<<GEMM_GRID, 256, 0, stream>>>(h, Bt1, tl, troot);
    agg_kernel<false><<<AGG_GRID, 256, 0, stream>>>(tl, troot, prow, deg, peidx, bnsc + HID, bnsh + HID,
                                                    nullptr, nullptr, h, nullptr);
    gemm_kernel<HID, false><<<GEMM_GRID, 256, 0, stream>>>(h, Bt2, tl, troot);
    agg_kernel<true><<<AGG_GRID, 256, 0, stream>>>(tl, troot, prow, deg, peidx, bnsc + 2 * HID, bnsh + 2 * HID,
                                                   lin_w, lin_b, nullptr, out);
}